// Round 15
// baseline (126.799 us; speedup 1.0000x reference)
//
#include <hip/hip_runtime.h>
#include <hip/hip_bf16.h>

// Forbid FMA contraction for plain fp expressions in ALL device code below:
// the kNN ranking must bit-match the reference's uncontracted fp32 expression
//   pd[i,j] = 2*inner(i,j) - xx[i] - xx[j]
// (rounds 4/6/8/10/11/13/14 passed uncontracted; round 5 regressed when the
// compiler fused 2*inner-xxi into v_fma_f32). Explicit fmaf() calls are NOT
// affected by this pragma -- the approx prefilter exploits exactly that.
#pragma clang fp contract(off)

// B=4, N=4096, C=128, K=32. All fp32. top-K LARGEST pd, tie -> lowest index.
// Round 15: FUSE the Linear into the knn epilogue. Ledger across rounds shows
// a persistent ~25-30us gap between bench dur_us and the knn dispatch time
// that did NOT move when linear was rewritten (r14) -> the cost is in the
// extra dispatches + pooled's 8MB global round-trip, not in linear's body.
// Each block now: select -> pool into LDS -> out[d] = sum_c pool[c]*Wt[c][d]
// (coalesced Wt float4 reads, LDS-broadcast pool reads, 8-way reduction,
// coalesced final store). 2 kernels total; pooled never touches global.
// Selection core is r14-verbatim.

constexpr int NB   = 4;
constexpr int NP   = 4096;
constexpr int NC   = 128;
constexpr int NK   = 32;
constexpr int NT   = 256;
constexpr int PERT = NP / NT; // 16

__device__ __forceinline__ unsigned skew(unsigned d) { return d + (d >> 5); }

// ---------------------------------------------------------------------------
// Kernel P: blocks 0..63: xxw[b*NP+j] = (x*x + y*y) + z*z (uncontracted,
// bit-identical to reference xx). Block 64: Wt[c][d] = W[d][c].
// ---------------------------------------------------------------------------
__global__ __launch_bounds__(NT) void precompute_kernel(
    const float* __restrict__ xyz,    // [B,3,N]
    const float* __restrict__ W,      // [C,C]
    float* __restrict__ xxw,          // [B*NP]
    float* __restrict__ Wt)           // [C,C] transposed
{
    const int blk = blockIdx.x;
    const int t   = threadIdx.x;
    if (blk < 64) {
        const int g = blk * NT + t;                // 0 .. B*NP-1
        const int b = g >> 12;
        const int j = g & (NP - 1);
        const float* xb = xyz + (size_t)b * 3 * NP;
        const float x = xb[j];
        const float y = xb[NP + j];
        const float z = xb[2 * NP + j];
        xxw[g] = (x * x + y * y) + z * z;          // each op rounded (no FMA)
    } else {
        for (int e = t; e < NC * NC; e += NT) {
            const int d = e >> 7;
            const int c = e & (NC - 1);
            Wt[c * NC + d] = W[e];                 // coalesced read
        }
    }
}

// ---------------------------------------------------------------------------
// Kernel A (fused): per-query kNN + mean pool + Linear -> final row in d_out.
// ---------------------------------------------------------------------------
__global__ __launch_bounds__(NT) void knn_fused_kernel(
    const float* __restrict__ xyz,    // [B,3,N]
    const float* __restrict__ xxw,    // [B*NP]
    const float* __restrict__ feats,  // [B,N,C]
    const float* __restrict__ Wt,     // [C,C] transposed: Wt[c][d]
    float* __restrict__ out)          // [B*N, C] final output
{
    const int bi   = blockIdx.x;
    const int b    = bi >> 12;
    const int i    = bi & (NP - 1);
    const int t    = threadIdx.x;
    const int lane = t & 63;
    const int wid  = t >> 6;

    const float* xb  = xyz + (size_t)b * 3 * NP;
    const float* xxb = xxw + ((size_t)b << 12);

    const float qx  = xb[i];
    const float qy  = xb[NP + i];
    const float qz  = xb[2 * NP + i];
    const float xxi = xxb[i];

    // APPROX pd (fmaf) + running thread-max. |pd_a - pd_exact| <= ~1e-4.
    float pda[PERT];
    float tmax = -3.0e38f;
    #pragma unroll
    for (int m = 0; m < PERT; ++m) {
        const int j = m * NT + t;
        const float px = xb[j];
        const float py = xb[NP + j];
        const float pz = xb[2 * NP + j];
        const float xxj = xxb[j];               // 4B scalar, L1-resident
        const float inner_a = fmaf(qx, px, fmaf(qy, py, qz * pz));
        const float pd_a    = fmaf(2.0f, inner_a, -xxi) - xxj;
        pda[m] = pd_a;
        tmax = fmaxf(tmax, pd_a);
    }
    // bin of thread max: trunc(max(pd+24,0)*2^26) >> 20, 0..1536 (width 2^-6)
    const float qm = fmaxf(tmax + 24.0f, 0.0f) * 67108864.0f;  // *2^26, exact
    const unsigned dgmax = min(((unsigned)qm) >> 20, 1536u);

    __shared__ unsigned s_hist[1600];   // 1537 skewed bins (6.4 KiB)
    __shared__ int      s_sel[NK];
    __shared__ int      s_sj[256];
    __shared__ unsigned s_sk[256];
    __shared__ unsigned s_wtot[4];
    __shared__ unsigned s_scnt, s_digit;
    __shared__ float4   s_red4[NT];     // 4 KiB reduction (pool + linear)
    __shared__ float    s_pool[NC];     // pooled row (512 B)

    if (t == 0) { s_scnt = 0; s_digit = 0; }
    if (t < NK) s_sel[t] = 0;           // defensive: never leave garbage
    {   // wide zeroing: 400 uint4 across 256 threads
        uint4* hz = (uint4*)s_hist;
        for (int z = t; z < 400; z += NT) hz[z] = make_uint4(0u, 0u, 0u, 0u);
    }
    __syncthreads();

    // -- histogram of the 256 thread-maxima (1 atomic per thread) --
    atomicAdd(&s_hist[skew(dgmax)], 1u);
    __syncthreads();

    // -- block suffix scan, no s_G array: G via wave shfl + cross-wave tail --
    unsigned h[8];
    unsigned hsum = 0;
    #pragma unroll
    for (int e = 0; e < 8; ++e) {
        const unsigned bin = (unsigned)(t * 8 + e);
        h[e] = (bin <= 1536u) ? s_hist[skew(bin)] : 0u;   // clamp (r7 lesson)
        hsum += h[e];
    }
    unsigned v = hsum;   // becomes within-wave suffix sum (incl. self)
    #pragma unroll
    for (int off = 1; off < 64; off <<= 1) {
        const unsigned o = __shfl_down(v, off, 64);
        if (lane + off < 64) v += o;
    }
    if (lane == 0) s_wtot[wid] = v;
    __syncthreads();
    unsigned tail = 0;
    for (int w = wid + 1; w < 4; ++w) tail += s_wtot[w];
    const unsigned G  = v + tail;
    const unsigned nb = __shfl_down(G, 1, 64);
    // identity: next wave's G[0] == this wave's tail (so lane 63 uses tail)
    const unsigned Gn = (lane == 63) ? tail : nb;

    if (G >= (unsigned)NK && Gn < (unsigned)NK) {
        unsigned above = Gn;
        #pragma unroll
        for (int e = 7; e >= 0; --e) {
            if (above + h[e] >= (unsigned)NK) {
                s_digit = (unsigned)(t * 8 + e);
                break;
            }
            above += h[e];
        }
    }
    __syncthreads();

    // Conservative edge of bin D (width 2^-6; exact steps) minus approx
    // margin 2^-11 (>=4x the bounded ~1e-4 fmaf-vs-uncontracted gap).
    const unsigned D = s_digit;
    const float thr = (((float)D * 0.015625f - 24.0f) - 0x1p-18f) - 0x1p-11f;

    // -- survivor pass: push index only --
    #pragma unroll
    for (int m = 0; m < PERT; ++m) {
        if (pda[m] >= thr) {
            const unsigned p = atomicAdd(&s_scnt, 1u);
            if (p < 256u) s_sj[p] = m * NT + t;
        }
    }
    __syncthreads();

    const int sc = (int)min(s_scnt, 256u);

    // -- exact re-key: one thread per survivor, uncontracted reference bits --
    if (t < sc) {
        const int j = s_sj[t];
        const float px = xb[j];
        const float py = xb[NP + j];
        const float pz = xb[2 * NP + j];
        const float xxj   = xxb[j];
        const float inner = (qx * px + qy * py) + qz * pz;   // no FMA (pragma)
        const float pd    = (2.0f * inner - xxi) - xxj;      // no FMA (pragma)
        const unsigned u  = __float_as_uint(pd);
        s_sk[t] = (u & 0x80000000u) ? ~u : (u | 0x80000000u);
    }
    __syncthreads();

    // -- exact top-32 among survivors by (key desc, idx asc) --
    if (wid == 0) {
        if (sc <= 64) {
            unsigned long long comp = 0ull;   // padding sorts below all real
            if (lane < sc)
                comp = ((unsigned long long)s_sk[lane] << 32) |
                       (unsigned)(~(unsigned)s_sj[lane]);
            #pragma unroll
            for (int k = 2; k <= 64; k <<= 1) {
                #pragma unroll
                for (int jj = k >> 1; jj >= 1; jj >>= 1) {
                    const unsigned long long other = __shfl_xor(comp, jj, 64);
                    const bool dirDesc = ((lane & k) == 0);
                    const bool isLow   = ((lane & jj) == 0);
                    const bool wantMax = (dirDesc == isLow);
                    const bool otherBigger = other > comp;
                    comp = (wantMax == otherBigger) ? other : comp;
                }
            }
            if (lane < NK)
                s_sel[lane] = (int)(~(unsigned)(comp & 0xffffffffull));
        } else {
            // rare path (65..256 survivors): 4/lane, 32 extraction rounds
            unsigned long long c[4];
            #pragma unroll
            for (int q = 0; q < 4; ++q) {
                const int idx = lane + 64 * q;
                c[q] = (idx < sc)
                     ? (((unsigned long long)s_sk[idx] << 32) |
                        (unsigned)(~(unsigned)s_sj[idx]))
                     : 0ull;
            }
            for (int r = 0; r < NK; ++r) {
                unsigned long long w = c[0];
                #pragma unroll
                for (int q = 1; q < 4; ++q) if (c[q] > w) w = c[q];
                #pragma unroll
                for (int off = 32; off >= 1; off >>= 1) {
                    const unsigned long long o = __shfl_xor(w, off, 64);
                    if (o > w) w = o;
                }
                #pragma unroll
                for (int q = 0; q < 4; ++q) if (c[q] == w) c[q] = 0ull;
                if (lane == 0)
                    s_sel[r] = (int)(~(unsigned)(w & 0xffffffffull));
            }
        }
    }
    __syncthreads();

    // -- mean-pool into LDS: thread = (row-group rg, channel-group cg) --
    {
        const int cg = t & 31;    // channels 4*cg .. 4*cg+3
        const int rg = t >> 5;    // rows 4*rg .. 4*rg+3
        const float* fb = feats + (size_t)b * NP * NC;
        float ax = 0.f, ay = 0.f, az = 0.f, aw = 0.f;
        #pragma unroll
        for (int k = 0; k < 4; ++k) {
            const int j = s_sel[rg * 4 + k] & (NP - 1);   // fault-proof mask
            const float4 f = *(const float4*)&fb[(size_t)j * NC + cg * 4];
            ax += f.x; ay += f.y; az += f.z; aw += f.w;
        }
        s_red4[t] = make_float4(ax, ay, az, aw);
    }
    __syncthreads();
    if (t < 32) {
        float4 s = s_red4[t];
        #pragma unroll
        for (int g2 = 1; g2 < 8; ++g2) {
            const float4 o = s_red4[g2 * 32 + t];
            s.x += o.x; s.y += o.y; s.z += o.z; s.w += o.w;
        }
        const float inv = 1.0f / (float)NK;
        s.x *= inv; s.y *= inv; s.z *= inv; s.w *= inv;
        *(float4*)&s_pool[t * 4] = s;
    }
    __syncthreads();

    // -- fused Linear: out[d] = sum_c s_pool[c] * Wt[c][d] --
    // thread = (c-group t>>5 of 16 c's, d-group t&31 of 4 d's)
    {
        const int dg = t & 31;
        const int cg = t >> 5;
        const float4* Wt4 = (const float4*)Wt;   // row c = 32 float4
        float4 a = make_float4(0.f, 0.f, 0.f, 0.f);
        #pragma unroll
        for (int k = 0; k < 16; ++k) {
            const int c = cg * 16 + k;
            const float  p = s_pool[c];          // broadcast per half-wave
            const float4 w = Wt4[c * 32 + dg];   // coalesced 512B across lanes
            a.x = fmaf(p, w.x, a.x); a.y = fmaf(p, w.y, a.y);
            a.z = fmaf(p, w.z, a.z); a.w = fmaf(p, w.w, a.w);
        }
        s_red4[t] = a;
    }
    __syncthreads();
    if (t < 32) {
        float4 s = s_red4[t];
        #pragma unroll
        for (int g2 = 1; g2 < 8; ++g2) {
            const float4 o = s_red4[g2 * 32 + t];
            s.x += o.x; s.y += o.y; s.z += o.z; s.w += o.w;
        }
        *(float4*)&out[(size_t)bi * NC + t * 4] = s;
    }
}

// ---------------------------------------------------------------------------
// Fallback pair (ws-less): r14 knn (writes pooled to d_out) + old linear.
// ---------------------------------------------------------------------------
__global__ __launch_bounds__(NT) void knn_pool_plain_kernel(
    const float* __restrict__ xyz, const float* __restrict__ feats,
    float* __restrict__ pooled)
{
    const int bi = blockIdx.x, b = bi >> 12, i = bi & (NP - 1);
    const int t = threadIdx.x, lane = t & 63, wid = t >> 6;
    const float* xb = xyz + (size_t)b * 3 * NP;
    const float qx = xb[i], qy = xb[NP + i], qz = xb[2 * NP + i];
    const float xxi = (qx * qx + qy * qy) + qz * qz;
    float pda[PERT]; float tmax = -3.0e38f;
    #pragma unroll
    for (int m = 0; m < PERT; ++m) {
        const int j = m * NT + t;
        const float px = xb[j], py = xb[NP + j], pz = xb[2 * NP + j];
        const float xxj = (px * px + py * py) + pz * pz;
        const float inner_a = fmaf(qx, px, fmaf(qy, py, qz * pz));
        const float pd_a = fmaf(2.0f, inner_a, -xxi) - xxj;
        pda[m] = pd_a; tmax = fmaxf(tmax, pd_a);
    }
    const float qm = fmaxf(tmax + 24.0f, 0.0f) * 67108864.0f;
    const unsigned dgmax = min(((unsigned)qm) >> 20, 1536u);
    __shared__ unsigned s_hist[1600];
    __shared__ int s_sel[NK]; __shared__ int s_sj[256];
    __shared__ unsigned s_sk[256]; __shared__ unsigned s_wtot[4];
    __shared__ unsigned s_scnt, s_digit; __shared__ float4 s_red4[NT];
    if (t == 0) { s_scnt = 0; s_digit = 0; }
    if (t < NK) s_sel[t] = 0;
    { uint4* hz = (uint4*)s_hist;
      for (int z = t; z < 400; z += NT) hz[z] = make_uint4(0u,0u,0u,0u); }
    __syncthreads();
    atomicAdd(&s_hist[skew(dgmax)], 1u);
    __syncthreads();
    unsigned h[8]; unsigned hsum = 0;
    #pragma unroll
    for (int e = 0; e < 8; ++e) {
        const unsigned bin = (unsigned)(t * 8 + e);
        h[e] = (bin <= 1536u) ? s_hist[skew(bin)] : 0u; hsum += h[e];
    }
    unsigned v = hsum;
    #pragma unroll
    for (int off = 1; off < 64; off <<= 1) {
        const unsigned o = __shfl_down(v, off, 64);
        if (lane + off < 64) v += o;
    }
    if (lane == 0) s_wtot[wid] = v;
    __syncthreads();
    unsigned tail = 0;
    for (int w = wid + 1; w < 4; ++w) tail += s_wtot[w];
    const unsigned G = v + tail;
    const unsigned nbr = __shfl_down(G, 1, 64);
    const unsigned Gn = (lane == 63) ? tail : nbr;
    if (G >= (unsigned)NK && Gn < (unsigned)NK) {
        unsigned above = Gn;
        #pragma unroll
        for (int e = 7; e >= 0; --e) {
            if (above + h[e] >= (unsigned)NK) { s_digit = (unsigned)(t*8+e); break; }
            above += h[e];
        }
    }
    __syncthreads();
    const unsigned D = s_digit;
    const float thr = (((float)D * 0.015625f - 24.0f) - 0x1p-18f) - 0x1p-11f;
    #pragma unroll
    for (int m = 0; m < PERT; ++m) {
        if (pda[m] >= thr) {
            const unsigned p = atomicAdd(&s_scnt, 1u);
            if (p < 256u) s_sj[p] = m * NT + t;
        }
    }
    __syncthreads();
    const int sc = (int)min(s_scnt, 256u);
    if (t < sc) {
        const int j = s_sj[t];
        const float px = xb[j], py = xb[NP + j], pz = xb[2 * NP + j];
        const float xxj = (px * px + py * py) + pz * pz;
        const float inner = (qx * px + qy * py) + qz * pz;
        const float pd = (2.0f * inner - xxi) - xxj;
        const unsigned u = __float_as_uint(pd);
        s_sk[t] = (u & 0x80000000u) ? ~u : (u | 0x80000000u);
    }
    __syncthreads();
    if (wid == 0) {
        if (sc <= 64) {
            unsigned long long comp = 0ull;
            if (lane < sc)
                comp = ((unsigned long long)s_sk[lane] << 32) |
                       (unsigned)(~(unsigned)s_sj[lane]);
            #pragma unroll
            for (int k = 2; k <= 64; k <<= 1)
                #pragma unroll
                for (int jj = k >> 1; jj >= 1; jj >>= 1) {
                    const unsigned long long other = __shfl_xor(comp, jj, 64);
                    const bool wantMax = (((lane & k) == 0) == ((lane & jj) == 0));
                    comp = (wantMax == (other > comp)) ? other : comp;
                }
            if (lane < NK) s_sel[lane] = (int)(~(unsigned)(comp & 0xffffffffull));
        } else {
            unsigned long long c[4];
            #pragma unroll
            for (int q = 0; q < 4; ++q) {
                const int idx = lane + 64 * q;
                c[q] = (idx < sc) ? (((unsigned long long)s_sk[idx] << 32) |
                                     (unsigned)(~(unsigned)s_sj[idx])) : 0ull;
            }
            for (int r = 0; r < NK; ++r) {
                unsigned long long w = c[0];
                #pragma unroll
                for (int q = 1; q < 4; ++q) if (c[q] > w) w = c[q];
                #pragma unroll
                for (int off = 32; off >= 1; off >>= 1) {
                    const unsigned long long o = __shfl_xor(w, off, 64);
                    if (o > w) w = o;
                }
                #pragma unroll
                for (int q = 0; q < 4; ++q) if (c[q] == w) c[q] = 0ull;
                if (lane == 0) s_sel[r] = (int)(~(unsigned)(w & 0xffffffffull));
            }
        }
    }
    __syncthreads();
    const int cg = t & 31, rg = t >> 5;
    const float* fb = feats + (size_t)b * NP * NC;
    float ax = 0.f, ay = 0.f, az = 0.f, aw = 0.f;
    #pragma unroll
    for (int k = 0; k < 4; ++k) {
        const int j = s_sel[rg * 4 + k] & (NP - 1);
        const float4 f = *(const float4*)&fb[(size_t)j * NC + cg * 4];
        ax += f.x; ay += f.y; az += f.z; aw += f.w;
    }
    s_red4[t] = make_float4(ax, ay, az, aw);
    __syncthreads();
    if (t < 32) {
        float4 s = s_red4[t];
        #pragma unroll
        for (int g2 = 1; g2 < 8; ++g2) {
            const float4 o = s_red4[g2 * 32 + t];
            s.x += o.x; s.y += o.y; s.z += o.z; s.w += o.w;
        }
        const float inv = 1.0f / (float)NK;
        s.x *= inv; s.y *= inv; s.z *= inv; s.w *= inv;
        *(float4*)&pooled[(size_t)bi * NC + t * 4] = s;
    }
}

__global__ __launch_bounds__(NT) void linear_kernel(
    float* __restrict__ io, const float* __restrict__ W)
{
    const int t = threadIdx.x;
    const int row0 = blockIdx.x * 64;
    __shared__ float P[64 * NC];
    const float* src = io + (size_t)row0 * NC;
    #pragma unroll
    for (int m = 0; m < 8; ++m) {
        const int e4 = m * NT + t;
        *(float4*)&P[e4 * 4] = *(const float4*)&src[e4 * 4];
    }
    __syncthreads();
    const int d = t & (NC - 1);
    const int rbase = (t >> 7) * 32;
    float acc[32];
    #pragma unroll
    for (int k = 0; k < 32; ++k) acc[k] = 0.f;
    const float* Wd = W + (size_t)d * NC;
    for (int c4 = 0; c4 < NC / 4; ++c4) {
        const float4 w = *(const float4*)(Wd + c4 * 4);
        #pragma unroll
        for (int k = 0; k < 32; ++k) {
            const float4 pv = *(const float4*)&P[(rbase + k) * NC + c4 * 4];
            acc[k] = fmaf(pv.x, w.x, acc[k]);
            acc[k] = fmaf(pv.y, w.y, acc[k]);
            acc[k] = fmaf(pv.z, w.z, acc[k]);
            acc[k] = fmaf(pv.w, w.w, acc[k]);
        }
    }
    #pragma unroll
    for (int k = 0; k < 32; ++k)
        io[(size_t)(row0 + rbase + k) * NC + d] = acc[k];
}

// ---------------------------------------------------------------------------
extern "C" void kernel_launch(void* const* d_in, const int* in_sizes, int n_in,
                              void* d_out, int out_size, void* d_ws, size_t ws_size,
                              hipStream_t stream) {
    const float* xyz   = nullptr;  // 49152
    const float* feats = nullptr;  // 2097152
    const float* W     = nullptr;  // 16384
    for (int k = 0; k < n_in; ++k) {
        if      (in_sizes[k] == NB * 3 * NP)       xyz   = (const float*)d_in[k];
        else if (in_sizes[k] == NB * NP * NC)      feats = (const float*)d_in[k];
        else if (in_sizes[k] == NC * NC)           W     = (const float*)d_in[k];
    }
    float* out = (float*)d_out;

    const size_t need = sizeof(float) * (size_t)(NB * NP + NC * NC);
    if (ws_size >= need) {
        float* xxw = (float*)d_ws;                 // 64 KiB
        float* Wt  = (float*)d_ws + NB * NP;       // 64 KiB
        precompute_kernel<<<65, NT, 0, stream>>>(xyz, W, xxw, Wt);
        knn_fused_kernel<<<NB * NP, NT, 0, stream>>>(xyz, xxw, feats, Wt, out);
    } else {
        knn_pool_plain_kernel<<<NB * NP, NT, 0, stream>>>(xyz, feats, out);
        linear_kernel<<<NB * NP / 64, NT, 0, stream>>>(out, W);
    }
}

// Round 16
// 114.197 us; speedup vs baseline: 1.1104x; 1.1104x over previous
//
#include <hip/hip_runtime.h>
#include <hip/hip_bf16.h>

// Forbid FMA contraction for plain fp expressions in ALL device code below:
// the kNN ranking must bit-match the reference's uncontracted fp32 expression
//   pd[i,j] = 2*inner(i,j) - xx[i] - xx[j]
// (rounds 4/6/8/10/11/13/14 passed uncontracted; round 5 regressed when the
// compiler fused 2*inner-xxi into v_fma_f32). Explicit fmaf() calls are NOT
// affected by this pragma -- the approx prefilter exploits exactly that.
#pragma clang fp contract(off)

// B=4, N=4096, C=128, K=32. All fp32. top-K LARGEST pd, tie -> lowest index.
// Round 16: r14 3-kernel split restored (r15 fusion lost: per-block 64KB Wt
// re-reads = 1GB L2 ~ +30us in-kernel, vs ~24us of dispatch gap saved).
// Ledger pins r14's linear_t at ~20us (4x its ~5us floor: fma:load 8:1,
// 64MB Wt traffic). NEW linear: 512 blocks x 32 rows -> fma:load 16:1,
// Wt traffic 32MB, 2 blocks/CU. knn kernel is r14-VERBATIM (87us).

constexpr int NB   = 4;
constexpr int NP   = 4096;
constexpr int NC   = 128;
constexpr int NK   = 32;
constexpr int NT   = 256;
constexpr int PERT = NP / NT; // 16

__device__ __forceinline__ unsigned skew(unsigned d) { return d + (d >> 5); }

// ---------------------------------------------------------------------------
// Kernel P: blocks 0..63: xxw[b*NP+j] = (x*x + y*y) + z*z (uncontracted,
// bit-identical to reference xx). Block 64: Wt[c][d] = W[d][c].
// ---------------------------------------------------------------------------
__global__ __launch_bounds__(NT) void precompute_kernel(
    const float* __restrict__ xyz,    // [B,3,N]
    const float* __restrict__ W,      // [C,C]
    float* __restrict__ xxw,          // [B*NP]
    float* __restrict__ Wt)           // [C,C] transposed
{
    const int blk = blockIdx.x;
    const int t   = threadIdx.x;
    if (blk < 64) {
        const int g = blk * NT + t;                // 0 .. B*NP-1
        const int b = g >> 12;
        const int j = g & (NP - 1);
        const float* xb = xyz + (size_t)b * 3 * NP;
        const float x = xb[j];
        const float y = xb[NP + j];
        const float z = xb[2 * NP + j];
        xxw[g] = (x * x + y * y) + z * z;          // each op rounded (no FMA)
    } else {
        for (int e = t; e < NC * NC; e += NT) {
            const int d = e >> 7;
            const int c = e & (NC - 1);
            Wt[c * NC + d] = W[e];                 // coalesced read
        }
    }
}

// ---------------------------------------------------------------------------
// Kernel A: per-query kNN (approx prefilter + exact refine) + mean pool.
// (r14-verbatim)
// ---------------------------------------------------------------------------
template <bool USE_WS>
__global__ __launch_bounds__(NT) void knn_pool_kernel(
    const float* __restrict__ xyz,    // [B,3,N]
    const float* __restrict__ xxw,    // [B*NP] (USE_WS only)
    const float* __restrict__ feats,  // [B,N,C]
    float* __restrict__ pooled)       // [B*N, C] (d_out, fp32 temp)
{
    const int bi   = blockIdx.x;
    const int b    = bi >> 12;
    const int i    = bi & (NP - 1);
    const int t    = threadIdx.x;
    const int lane = t & 63;
    const int wid  = t >> 6;

    const float* xb  = xyz + (size_t)b * 3 * NP;
    const float* xxb = USE_WS ? (xxw + ((size_t)b << 12)) : nullptr;

    const float qx = xb[i];
    const float qy = xb[NP + i];
    const float qz = xb[2 * NP + i];
    float xxi;
    if constexpr (USE_WS) xxi = xxb[i];
    else                  xxi = (qx * qx + qy * qy) + qz * qz;

    // APPROX pd (fmaf) + running thread-max. |pd_a - pd_exact| <= ~1e-4.
    float pda[PERT];
    float tmax = -3.0e38f;
    #pragma unroll
    for (int m = 0; m < PERT; ++m) {
        const int j = m * NT + t;
        const float px = xb[j];
        const float py = xb[NP + j];
        const float pz = xb[2 * NP + j];
        float xxj;
        if constexpr (USE_WS) xxj = xxb[j];     // 4B scalar, L1-resident
        else                  xxj = (px * px + py * py) + pz * pz;
        const float inner_a = fmaf(qx, px, fmaf(qy, py, qz * pz));
        const float pd_a    = fmaf(2.0f, inner_a, -xxi) - xxj;
        pda[m] = pd_a;
        tmax = fmaxf(tmax, pd_a);
    }
    // bin of thread max: trunc(max(pd+24,0)*2^26) >> 20, 0..1536 (width 2^-6)
    const float qm = fmaxf(tmax + 24.0f, 0.0f) * 67108864.0f;  // *2^26, exact
    const unsigned dgmax = min(((unsigned)qm) >> 20, 1536u);

    __shared__ unsigned s_hist[1600];   // 1537 skewed bins (6.4 KiB)
    __shared__ int      s_sel[NK];
    __shared__ int      s_sj[256];
    __shared__ unsigned s_sk[256];
    __shared__ unsigned s_wtot[4];
    __shared__ unsigned s_scnt, s_digit;
    __shared__ float4   s_red4[NT];     // 4 KiB pool reduction

    if (t == 0) { s_scnt = 0; s_digit = 0; }
    if (t < NK) s_sel[t] = 0;           // defensive: never leave garbage
    {   // wide zeroing: 400 uint4 across 256 threads
        uint4* hz = (uint4*)s_hist;
        for (int z = t; z < 400; z += NT) hz[z] = make_uint4(0u, 0u, 0u, 0u);
    }
    __syncthreads();

    // -- histogram of the 256 thread-maxima (1 atomic per thread) --
    atomicAdd(&s_hist[skew(dgmax)], 1u);
    __syncthreads();

    // -- block suffix scan, no s_G array: G via wave shfl + cross-wave tail --
    unsigned h[8];
    unsigned hsum = 0;
    #pragma unroll
    for (int e = 0; e < 8; ++e) {
        const unsigned bin = (unsigned)(t * 8 + e);
        h[e] = (bin <= 1536u) ? s_hist[skew(bin)] : 0u;   // clamp (r7 lesson)
        hsum += h[e];
    }
    unsigned v = hsum;   // becomes within-wave suffix sum (incl. self)
    #pragma unroll
    for (int off = 1; off < 64; off <<= 1) {
        const unsigned o = __shfl_down(v, off, 64);
        if (lane + off < 64) v += o;
    }
    if (lane == 0) s_wtot[wid] = v;
    __syncthreads();
    unsigned tail = 0;
    for (int w = wid + 1; w < 4; ++w) tail += s_wtot[w];
    const unsigned G  = v + tail;
    const unsigned nb = __shfl_down(G, 1, 64);
    // identity: next wave's G[0] == this wave's tail (so lane 63 uses tail)
    const unsigned Gn = (lane == 63) ? tail : nb;

    if (G >= (unsigned)NK && Gn < (unsigned)NK) {
        unsigned above = Gn;
        #pragma unroll
        for (int e = 7; e >= 0; --e) {
            if (above + h[e] >= (unsigned)NK) {
                s_digit = (unsigned)(t * 8 + e);
                break;
            }
            above += h[e];
        }
    }
    __syncthreads();

    // Conservative edge of bin D (width 2^-6; exact steps) minus approx
    // margin 2^-11 (>=4x the bounded ~1e-4 fmaf-vs-uncontracted gap).
    const unsigned D = s_digit;
    const float thr = (((float)D * 0.015625f - 24.0f) - 0x1p-18f) - 0x1p-11f;

    // -- survivor pass: push index only --
    #pragma unroll
    for (int m = 0; m < PERT; ++m) {
        if (pda[m] >= thr) {
            const unsigned p = atomicAdd(&s_scnt, 1u);
            if (p < 256u) s_sj[p] = m * NT + t;
        }
    }
    __syncthreads();

    const int sc = (int)min(s_scnt, 256u);

    // -- exact re-key: one thread per survivor, uncontracted reference bits --
    if (t < sc) {
        const int j = s_sj[t];
        const float px = xb[j];
        const float py = xb[NP + j];
        const float pz = xb[2 * NP + j];
        float xxj;
        if constexpr (USE_WS) xxj = xxb[j];
        else                  xxj = (px * px + py * py) + pz * pz;
        const float inner = (qx * px + qy * py) + qz * pz;   // no FMA (pragma)
        const float pd    = (2.0f * inner - xxi) - xxj;      // no FMA (pragma)
        const unsigned u  = __float_as_uint(pd);
        s_sk[t] = (u & 0x80000000u) ? ~u : (u | 0x80000000u);
    }
    __syncthreads();

    // -- exact top-32 among survivors by (key desc, idx asc) --
    if (wid == 0) {
        if (sc <= 64) {
            unsigned long long comp = 0ull;   // padding sorts below all real
            if (lane < sc)
                comp = ((unsigned long long)s_sk[lane] << 32) |
                       (unsigned)(~(unsigned)s_sj[lane]);
            #pragma unroll
            for (int k = 2; k <= 64; k <<= 1) {
                #pragma unroll
                for (int jj = k >> 1; jj >= 1; jj >>= 1) {
                    const unsigned long long other = __shfl_xor(comp, jj, 64);
                    const bool dirDesc = ((lane & k) == 0);
                    const bool isLow   = ((lane & jj) == 0);
                    const bool wantMax = (dirDesc == isLow);
                    const bool otherBigger = other > comp;
                    comp = (wantMax == otherBigger) ? other : comp;
                }
            }
            if (lane < NK)
                s_sel[lane] = (int)(~(unsigned)(comp & 0xffffffffull));
        } else {
            // rare path (65..256 survivors): 4/lane, 32 extraction rounds
            unsigned long long c[4];
            #pragma unroll
            for (int q = 0; q < 4; ++q) {
                const int idx = lane + 64 * q;
                c[q] = (idx < sc)
                     ? (((unsigned long long)s_sk[idx] << 32) |
                        (unsigned)(~(unsigned)s_sj[idx]))
                     : 0ull;
            }
            for (int r = 0; r < NK; ++r) {
                unsigned long long w = c[0];
                #pragma unroll
                for (int q = 1; q < 4; ++q) if (c[q] > w) w = c[q];
                #pragma unroll
                for (int off = 32; off >= 1; off >>= 1) {
                    const unsigned long long o = __shfl_xor(w, off, 64);
                    if (o > w) w = o;
                }
                #pragma unroll
                for (int q = 0; q < 4; ++q) if (c[q] == w) c[q] = 0ull;
                if (lane == 0)
                    s_sel[r] = (int)(~(unsigned)(w & 0xffffffffull));
            }
        }
    }
    __syncthreads();

    // -- mean-pool, vectorized: thread = (row-group rg, channel-group cg) --
    const int cg = t & 31;    // channels 4*cg .. 4*cg+3
    const int rg = t >> 5;    // rows 4*rg .. 4*rg+3
    const float* fb = feats + (size_t)b * NP * NC;
    float ax = 0.f, ay = 0.f, az = 0.f, aw = 0.f;
    #pragma unroll
    for (int k = 0; k < 4; ++k) {
        const int j = s_sel[rg * 4 + k] & (NP - 1);   // fault-proof mask
        const float4 f = *(const float4*)&fb[(size_t)j * NC + cg * 4];
        ax += f.x; ay += f.y; az += f.z; aw += f.w;
    }
    s_red4[t] = make_float4(ax, ay, az, aw);
    __syncthreads();
    if (t < 32) {
        float4 s = s_red4[t];
        #pragma unroll
        for (int g2 = 1; g2 < 8; ++g2) {
            const float4 o = s_red4[g2 * 32 + t];
            s.x += o.x; s.y += o.y; s.z += o.z; s.w += o.w;
        }
        const float inv = 1.0f / (float)NK;
        s.x *= inv; s.y *= inv; s.z *= inv; s.w *= inv;
        *(float4*)&pooled[(size_t)bi * NC + t * 4] = s;
    }
}

// ---------------------------------------------------------------------------
// Kernel B (v2): in-place Linear, 512 blocks x 32 rows, 2 blocks/CU.
// thread = (d-group t&31 of 4 d's, row-group t>>5 of 4 rows) -> 16 acc.
// Per c: 1 coalesced Wt float4 load + 4 LDS broadcasts + 16 fma (16:1 ratio).
// Wt traffic 512 x 64KB = 32MB L2. Full ascending-c sums -> same bits as r14.
// ---------------------------------------------------------------------------
constexpr int LROWS = 32;
__global__ __launch_bounds__(NT) void linear_v2_kernel(
    float* __restrict__ io,           // [B*N, C] fp32, in-place
    const float* __restrict__ Wt)     // [C, C] transposed: Wt[c][d]
{
    const int t    = threadIdx.x;
    const int row0 = blockIdx.x * LROWS;

    __shared__ float P[LROWS * NC];   // 16 KiB

    const float4* src4 = (const float4*)(io + (size_t)row0 * NC);
    #pragma unroll
    for (int m = 0; m < 4; ++m)
        ((float4*)P)[m * NT + t] = src4[m * NT + t];
    __syncthreads();

    const int dg = t & 31;            // d = 4*dg .. 4*dg+3
    const int rg = t >> 5;            // rows 4*rg .. 4*rg+3

    float4 a0 = make_float4(0.f,0.f,0.f,0.f);
    float4 a1 = make_float4(0.f,0.f,0.f,0.f);
    float4 a2 = make_float4(0.f,0.f,0.f,0.f);
    float4 a3 = make_float4(0.f,0.f,0.f,0.f);
    const float4* Wt4 = (const float4*)Wt;   // row c = 32 float4
    const float*  Pr  = P + rg * 4 * NC;

    #pragma unroll 4
    for (int c = 0; c < NC; ++c) {
        const float4 w = Wt4[c * 32 + dg];   // coalesced across 32 lanes
        const float p0 = Pr[c];              // LDS broadcast per lane-group
        const float p1 = Pr[NC + c];
        const float p2 = Pr[2 * NC + c];
        const float p3 = Pr[3 * NC + c];
        a0.x = fmaf(p0, w.x, a0.x); a0.y = fmaf(p0, w.y, a0.y);
        a0.z = fmaf(p0, w.z, a0.z); a0.w = fmaf(p0, w.w, a0.w);
        a1.x = fmaf(p1, w.x, a1.x); a1.y = fmaf(p1, w.y, a1.y);
        a1.z = fmaf(p1, w.z, a1.z); a1.w = fmaf(p1, w.w, a1.w);
        a2.x = fmaf(p2, w.x, a2.x); a2.y = fmaf(p2, w.y, a2.y);
        a2.z = fmaf(p2, w.z, a2.z); a2.w = fmaf(p2, w.w, a2.w);
        a3.x = fmaf(p3, w.x, a3.x); a3.y = fmaf(p3, w.y, a3.y);
        a3.z = fmaf(p3, w.z, a3.z); a3.w = fmaf(p3, w.w, a3.w);
    }

    float4* dst4 = (float4*)(io + (size_t)row0 * NC);
    const int r4 = rg * 4;
    dst4[(r4 + 0) * 32 + dg] = a0;    // all staging reads done pre-barrier
    dst4[(r4 + 1) * 32 + dg] = a1;
    dst4[(r4 + 2) * 32 + dg] = a2;
    dst4[(r4 + 3) * 32 + dg] = a3;
}

// ---------------------------------------------------------------------------
// Fallback (ws-less): old 64-row in-place linear reading W directly.
// ---------------------------------------------------------------------------
__global__ __launch_bounds__(NT) void linear_kernel(
    float* __restrict__ io, const float* __restrict__ W)
{
    const int t = threadIdx.x;
    const int row0 = blockIdx.x * 64;
    __shared__ float P[64 * NC];
    const float* src = io + (size_t)row0 * NC;
    #pragma unroll
    for (int m = 0; m < 8; ++m) {
        const int e4 = m * NT + t;
        *(float4*)&P[e4 * 4] = *(const float4*)&src[e4 * 4];
    }
    __syncthreads();
    const int d = t & (NC - 1);
    const int rbase = (t >> 7) * 32;
    float acc[32];
    #pragma unroll
    for (int k = 0; k < 32; ++k) acc[k] = 0.f;
    const float* Wd = W + (size_t)d * NC;
    for (int c4 = 0; c4 < NC / 4; ++c4) {
        const float4 w = *(const float4*)(Wd + c4 * 4);
        #pragma unroll
        for (int k = 0; k < 32; ++k) {
            const float4 pv = *(const float4*)&P[(rbase + k) * NC + c4 * 4];
            acc[k] = fmaf(pv.x, w.x, acc[k]);
            acc[k] = fmaf(pv.y, w.y, acc[k]);
            acc[k] = fmaf(pv.z, w.z, acc[k]);
            acc[k] = fmaf(pv.w, w.w, acc[k]);
        }
    }
    #pragma unroll
    for (int k = 0; k < 32; ++k)
        io[(size_t)(row0 + rbase + k) * NC + d] = acc[k];
}

// ---------------------------------------------------------------------------
extern "C" void kernel_launch(void* const* d_in, const int* in_sizes, int n_in,
                              void* d_out, int out_size, void* d_ws, size_t ws_size,
                              hipStream_t stream) {
    const float* xyz   = nullptr;  // 49152
    const float* feats = nullptr;  // 2097152
    const float* W     = nullptr;  // 16384
    for (int k = 0; k < n_in; ++k) {
        if      (in_sizes[k] == NB * 3 * NP)       xyz   = (const float*)d_in[k];
        else if (in_sizes[k] == NB * NP * NC)      feats = (const float*)d_in[k];
        else if (in_sizes[k] == NC * NC)           W     = (const float*)d_in[k];
    }
    float* out = (float*)d_out;

    const size_t need = sizeof(float) * (size_t)(NB * NP + NC * NC);
    if (ws_size >= need) {
        float* xxw = (float*)d_ws;                 // 64 KiB
        float* Wt  = (float*)d_ws + NB * NP;       // 64 KiB
        precompute_kernel<<<65, NT, 0, stream>>>(xyz, W, xxw, Wt);
        knn_pool_kernel<true><<<NB * NP, NT, 0, stream>>>(xyz, xxw, feats, out);
        linear_v2_kernel<<<NB * NP / LROWS, NT, 0, stream>>>(out, Wt);
    } else {
        knn_pool_kernel<false><<<NB * NP, NT, 0, stream>>>(xyz, nullptr, feats, out);
        linear_kernel<<<NB * NP / 64, NT, 0, stream>>>(out, W);
    }
}

// Round 17
// 104.891 us; speedup vs baseline: 1.2089x; 1.0887x over previous
//
#include <hip/hip_runtime.h>
#include <hip/hip_bf16.h>

// Forbid FMA contraction for plain fp expressions in ALL device code below:
// the kNN ranking must bit-match the reference's uncontracted fp32 expression
//   pd[i,j] = 2*inner(i,j) - xx[i] - xx[j]
// (rounds 4/6/8/10/11/13/14/16 passed uncontracted; round 5 regressed when
// the compiler fused 2*inner-xxi into v_fma_f32). Explicit fmaf() calls are
// NOT affected by this pragma -- the approx prefilter exploits exactly that.
#pragma clang fp contract(off)

// B=4, N=4096, C=128, K=32. All fp32. top-K LARGEST pd, tie -> lowest index.
// Round 17: attack knn's VMEM-instruction bound (64 scalar wave-loads/thread
// in the main loop ~ 50us of L1 service, co-dominant with 44us VALU):
//   - thread handles 16 CONSECUTIVE candidates -> per quad of 4: three
//     float4 plane loads (x,y,z) instead of 16 scalar loads (VMEM 64->12);
//     xx_j recomputed inline with fmaf (covered by the 2^-11 approx margin);
//     exact re-key computes uncontracted xx for survivors only.
//   - xxw array + precompute dispatch DELETED; W-transpose folded into the
//     last knn block (stream-ordered before linear) -> 2 dispatches total.
//   - linear_v3: P staged rows read as float4 (ds_read_b128, LDS inst /4),
//     same ascending-c fma order (bit-identical output to v2).
// Selection machinery (histogram of thread-maxima, suffix scan, conservative
// edge, survivor gather, exact bitonic refinement) is r14-VERBATIM.

constexpr int NB   = 4;
constexpr int NP   = 4096;
constexpr int NC   = 128;
constexpr int NK   = 32;
constexpr int NT   = 256;
constexpr int PERT = NP / NT; // 16

__device__ __forceinline__ unsigned skew(unsigned d) { return d + (d >> 5); }

// approx pd for one candidate (fmaf allowed; bounded vs exact by ~1e-4)
__device__ __forceinline__ void pd_approx(
    float x, float y, float z, float qx, float qy, float qz, float xxi,
    float& pd_out, float& tmax)
{
    const float xxj   = fmaf(x, x, fmaf(y, y, z * z));
    const float inner = fmaf(qx, x, fmaf(qy, y, qz * z));
    const float pd    = fmaf(2.0f, inner, -xxi) - xxj;
    pd_out = pd;
    tmax = fmaxf(tmax, pd);
}

// ---------------------------------------------------------------------------
// Kernel A: per-query kNN (approx prefilter + exact refine) + mean pool.
// Last block additionally transposes W -> Wt for the linear kernel.
// ---------------------------------------------------------------------------
__global__ __launch_bounds__(NT) void knn_pool_kernel(
    const float* __restrict__ xyz,    // [B,3,N]
    const float* __restrict__ feats,  // [B,N,C]
    const float* __restrict__ W,      // [C,C] (only used by last block)
    float* __restrict__ Wt,           // [C,C] transposed out (or nullptr)
    float* __restrict__ pooled)       // [B*N, C] (d_out, fp32 temp)
{
    const int bi   = blockIdx.x;
    const int b    = bi >> 12;
    const int i    = bi & (NP - 1);
    const int t    = threadIdx.x;
    const int lane = t & 63;
    const int wid  = t >> 6;

    // fold W-transpose into the last block (ready before linear launches)
    if (Wt != nullptr && bi == NB * NP - 1) {
        for (int e = t; e < NC * NC; e += NT) {
            const int d = e >> 7;
            const int c = e & (NC - 1);
            Wt[c * NC + d] = W[e];               // coalesced read
        }
    }

    const float* xb = xyz + (size_t)b * 3 * NP;

    const float qx  = xb[i];
    const float qy  = xb[NP + i];
    const float qz  = xb[2 * NP + i];
    const float xxi = (qx * qx + qy * qy) + qz * qz;  // uncontracted (exact)

    // main loop: 4 quads of 4 consecutive candidates, float4 plane loads
    float pda[PERT];
    float tmax = -3.0e38f;
    const int j0 = t * PERT;    // candidates j0 .. j0+15
    #pragma unroll
    for (int q = 0; q < 4; ++q) {
        const float4 X = *(const float4*)&xb[j0 + 4 * q];
        const float4 Y = *(const float4*)&xb[NP + j0 + 4 * q];
        const float4 Z = *(const float4*)&xb[2 * NP + j0 + 4 * q];
        pd_approx(X.x, Y.x, Z.x, qx, qy, qz, xxi, pda[4 * q + 0], tmax);
        pd_approx(X.y, Y.y, Z.y, qx, qy, qz, xxi, pda[4 * q + 1], tmax);
        pd_approx(X.z, Y.z, Z.z, qx, qy, qz, xxi, pda[4 * q + 2], tmax);
        pd_approx(X.w, Y.w, Z.w, qx, qy, qz, xxi, pda[4 * q + 3], tmax);
    }
    // bin of thread max: trunc(max(pd+24,0)*2^26) >> 20, 0..1536 (width 2^-6)
    const float qm = fmaxf(tmax + 24.0f, 0.0f) * 67108864.0f;  // *2^26, exact
    const unsigned dgmax = min(((unsigned)qm) >> 20, 1536u);

    __shared__ unsigned s_hist[1600];   // 1537 skewed bins (6.4 KiB)
    __shared__ int      s_sel[NK];
    __shared__ int      s_sj[256];
    __shared__ unsigned s_sk[256];
    __shared__ unsigned s_wtot[4];
    __shared__ unsigned s_scnt, s_digit;
    __shared__ float4   s_red4[NT];     // 4 KiB pool reduction

    if (t == 0) { s_scnt = 0; s_digit = 0; }
    if (t < NK) s_sel[t] = 0;           // defensive: never leave garbage
    {   // wide zeroing: 400 uint4 across 256 threads
        uint4* hz = (uint4*)s_hist;
        for (int z = t; z < 400; z += NT) hz[z] = make_uint4(0u, 0u, 0u, 0u);
    }
    __syncthreads();

    // -- histogram of the 256 thread-maxima (1 atomic per thread) --
    atomicAdd(&s_hist[skew(dgmax)], 1u);
    __syncthreads();

    // -- block suffix scan, no s_G array: G via wave shfl + cross-wave tail --
    unsigned h[8];
    unsigned hsum = 0;
    #pragma unroll
    for (int e = 0; e < 8; ++e) {
        const unsigned bin = (unsigned)(t * 8 + e);
        h[e] = (bin <= 1536u) ? s_hist[skew(bin)] : 0u;   // clamp (r7 lesson)
        hsum += h[e];
    }
    unsigned v = hsum;   // becomes within-wave suffix sum (incl. self)
    #pragma unroll
    for (int off = 1; off < 64; off <<= 1) {
        const unsigned o = __shfl_down(v, off, 64);
        if (lane + off < 64) v += o;
    }
    if (lane == 0) s_wtot[wid] = v;
    __syncthreads();
    unsigned tail = 0;
    for (int w = wid + 1; w < 4; ++w) tail += s_wtot[w];
    const unsigned G  = v + tail;
    const unsigned nb = __shfl_down(G, 1, 64);
    // identity: next wave's G[0] == this wave's tail (so lane 63 uses tail)
    const unsigned Gn = (lane == 63) ? tail : nb;

    if (G >= (unsigned)NK && Gn < (unsigned)NK) {
        unsigned above = Gn;
        #pragma unroll
        for (int e = 7; e >= 0; --e) {
            if (above + h[e] >= (unsigned)NK) {
                s_digit = (unsigned)(t * 8 + e);
                break;
            }
            above += h[e];
        }
    }
    __syncthreads();

    // Conservative edge of bin D (width 2^-6; exact steps) minus approx
    // margin 2^-11 (>=4x the bounded ~1e-4 fmaf-vs-uncontracted gap).
    const unsigned D = s_digit;
    const float thr = (((float)D * 0.015625f - 24.0f) - 0x1p-18f) - 0x1p-11f;

    // -- survivor pass: push index only --
    #pragma unroll
    for (int m = 0; m < PERT; ++m) {
        if (pda[m] >= thr) {
            const unsigned p = atomicAdd(&s_scnt, 1u);
            if (p < 256u) s_sj[p] = j0 + m;
        }
    }
    __syncthreads();

    const int sc = (int)min(s_scnt, 256u);

    // -- exact re-key: one thread per survivor, uncontracted reference bits --
    if (t < sc) {
        const int j = s_sj[t];
        const float px = xb[j];
        const float py = xb[NP + j];
        const float pz = xb[2 * NP + j];
        const float xxj   = (px * px + py * py) + pz * pz;   // no FMA (pragma)
        const float inner = (qx * px + qy * py) + qz * pz;   // no FMA (pragma)
        const float pd    = (2.0f * inner - xxi) - xxj;      // no FMA (pragma)
        const unsigned u  = __float_as_uint(pd);
        s_sk[t] = (u & 0x80000000u) ? ~u : (u | 0x80000000u);
    }
    __syncthreads();

    // -- exact top-32 among survivors by (key desc, idx asc) --
    if (wid == 0) {
        if (sc <= 64) {
            unsigned long long comp = 0ull;   // padding sorts below all real
            if (lane < sc)
                comp = ((unsigned long long)s_sk[lane] << 32) |
                       (unsigned)(~(unsigned)s_sj[lane]);
            #pragma unroll
            for (int k = 2; k <= 64; k <<= 1) {
                #pragma unroll
                for (int jj = k >> 1; jj >= 1; jj >>= 1) {
                    const unsigned long long other = __shfl_xor(comp, jj, 64);
                    const bool dirDesc = ((lane & k) == 0);
                    const bool isLow   = ((lane & jj) == 0);
                    const bool wantMax = (dirDesc == isLow);
                    const bool otherBigger = other > comp;
                    comp = (wantMax == otherBigger) ? other : comp;
                }
            }
            if (lane < NK)
                s_sel[lane] = (int)(~(unsigned)(comp & 0xffffffffull));
        } else {
            // rare path (65..256 survivors): 4/lane, 32 extraction rounds
            unsigned long long c[4];
            #pragma unroll
            for (int q = 0; q < 4; ++q) {
                const int idx = lane + 64 * q;
                c[q] = (idx < sc)
                     ? (((unsigned long long)s_sk[idx] << 32) |
                        (unsigned)(~(unsigned)s_sj[idx]))
                     : 0ull;
            }
            for (int r = 0; r < NK; ++r) {
                unsigned long long w = c[0];
                #pragma unroll
                for (int q = 1; q < 4; ++q) if (c[q] > w) w = c[q];
                #pragma unroll
                for (int off = 32; off >= 1; off >>= 1) {
                    const unsigned long long o = __shfl_xor(w, off, 64);
                    if (o > w) w = o;
                }
                #pragma unroll
                for (int q = 0; q < 4; ++q) if (c[q] == w) c[q] = 0ull;
                if (lane == 0)
                    s_sel[r] = (int)(~(unsigned)(w & 0xffffffffull));
            }
        }
    }
    __syncthreads();

    // -- mean-pool, vectorized: thread = (row-group rg, channel-group cg) --
    const int cg = t & 31;    // channels 4*cg .. 4*cg+3
    const int rg = t >> 5;    // rows 4*rg .. 4*rg+3
    const float* fb = feats + (size_t)b * NP * NC;
    float ax = 0.f, ay = 0.f, az = 0.f, aw = 0.f;
    #pragma unroll
    for (int k = 0; k < 4; ++k) {
        const int j = s_sel[rg * 4 + k] & (NP - 1);   // fault-proof mask
        const float4 f = *(const float4*)&fb[(size_t)j * NC + cg * 4];
        ax += f.x; ay += f.y; az += f.z; aw += f.w;
    }
    s_red4[t] = make_float4(ax, ay, az, aw);
    __syncthreads();
    if (t < 32) {
        float4 s = s_red4[t];
        #pragma unroll
        for (int g2 = 1; g2 < 8; ++g2) {
            const float4 o = s_red4[g2 * 32 + t];
            s.x += o.x; s.y += o.y; s.z += o.z; s.w += o.w;
        }
        const float inv = 1.0f / (float)NK;
        s.x *= inv; s.y *= inv; s.z *= inv; s.w *= inv;
        *(float4*)&pooled[(size_t)bi * NC + t * 4] = s;
    }
}

// ---------------------------------------------------------------------------
// Kernel B (v3): in-place Linear, 512 blocks x 32 rows, 2 blocks/CU.
// P rows read as float4 (ds_read_b128, 4 c's per read). Per c-quad:
// 4 b128 LDS reads + 4 coalesced Wt float4 loads + 64 fma. Ascending-c fma
// order preserved -> bit-identical to the r16 linear_v2 output.
// ---------------------------------------------------------------------------
constexpr int LROWS = 32;
__global__ __launch_bounds__(NT) void linear_v3_kernel(
    float* __restrict__ io,           // [B*N, C] fp32, in-place
    const float* __restrict__ Wt)     // [C, C] transposed: Wt[c][d]
{
    const int t    = threadIdx.x;
    const int row0 = blockIdx.x * LROWS;

    __shared__ float P[LROWS * NC];   // 16 KiB

    const float4* src4 = (const float4*)(io + (size_t)row0 * NC);
    #pragma unroll
    for (int m = 0; m < 4; ++m)
        ((float4*)P)[m * NT + t] = src4[m * NT + t];
    __syncthreads();

    const int dg = t & 31;            // d = 4*dg .. 4*dg+3
    const int rg = t >> 5;            // rows 4*rg .. 4*rg+3

    float4 a0 = make_float4(0.f,0.f,0.f,0.f);
    float4 a1 = make_float4(0.f,0.f,0.f,0.f);
    float4 a2 = make_float4(0.f,0.f,0.f,0.f);
    float4 a3 = make_float4(0.f,0.f,0.f,0.f);
    const float4* Wt4 = (const float4*)Wt;   // row c = 32 float4
    const float*  Pr  = P + rg * 4 * NC;

#define LSTEP(K, PC)                                                          \
    {                                                                         \
        const float4 w = Wt4[(c4 * 4 + K) * 32 + dg];                         \
        a0.x = fmaf(p0.PC, w.x, a0.x); a0.y = fmaf(p0.PC, w.y, a0.y);         \
        a0.z = fmaf(p0.PC, w.z, a0.z); a0.w = fmaf(p0.PC, w.w, a0.w);         \
        a1.x = fmaf(p1.PC, w.x, a1.x); a1.y = fmaf(p1.PC, w.y, a1.y);         \
        a1.z = fmaf(p1.PC, w.z, a1.z); a1.w = fmaf(p1.PC, w.w, a1.w);         \
        a2.x = fmaf(p2.PC, w.x, a2.x); a2.y = fmaf(p2.PC, w.y, a2.y);         \
        a2.z = fmaf(p2.PC, w.z, a2.z); a2.w = fmaf(p2.PC, w.w, a2.w);         \
        a3.x = fmaf(p3.PC, w.x, a3.x); a3.y = fmaf(p3.PC, w.y, a3.y);         \
        a3.z = fmaf(p3.PC, w.z, a3.z); a3.w = fmaf(p3.PC, w.w, a3.w);         \
    }

    #pragma unroll 4
    for (int c4 = 0; c4 < NC / 4; ++c4) {
        const float4 p0 = *(const float4*)&Pr[c4 * 4];            // b128 reads
        const float4 p1 = *(const float4*)&Pr[NC + c4 * 4];
        const float4 p2 = *(const float4*)&Pr[2 * NC + c4 * 4];
        const float4 p3 = *(const float4*)&Pr[3 * NC + c4 * 4];
        LSTEP(0, x) LSTEP(1, y) LSTEP(2, z) LSTEP(3, w)
    }
#undef LSTEP

    float4* dst4 = (float4*)(io + (size_t)row0 * NC);
    const int r4 = rg * 4;
    dst4[(r4 + 0) * 32 + dg] = a0;    // all staging reads done pre-barrier
    dst4[(r4 + 1) * 32 + dg] = a1;
    dst4[(r4 + 2) * 32 + dg] = a2;
    dst4[(r4 + 3) * 32 + dg] = a3;
}

// ---------------------------------------------------------------------------
// Fallback (ws-less): old 64-row in-place linear reading W directly.
// ---------------------------------------------------------------------------
__global__ __launch_bounds__(NT) void linear_kernel(
    float* __restrict__ io, const float* __restrict__ W)
{
    const int t = threadIdx.x;
    const int row0 = blockIdx.x * 64;
    __shared__ float P[64 * NC];
    const float* src = io + (size_t)row0 * NC;
    #pragma unroll
    for (int m = 0; m < 8; ++m) {
        const int e4 = m * NT + t;
        *(float4*)&P[e4 * 4] = *(const float4*)&src[e4 * 4];
    }
    __syncthreads();
    const int d = t & (NC - 1);
    const int rbase = (t >> 7) * 32;
    float acc[32];
    #pragma unroll
    for (int k = 0; k < 32; ++k) acc[k] = 0.f;
    const float* Wd = W + (size_t)d * NC;
    for (int c4 = 0; c4 < NC / 4; ++c4) {
        const float4 w = *(const float4*)(Wd + c4 * 4);
        #pragma unroll
        for (int k = 0; k < 32; ++k) {
            const float4 pv = *(const float4*)&P[(rbase + k) * NC + c4 * 4];
            acc[k] = fmaf(pv.x, w.x, acc[k]);
            acc[k] = fmaf(pv.y, w.y, acc[k]);
            acc[k] = fmaf(pv.z, w.z, acc[k]);
            acc[k] = fmaf(pv.w, w.w, acc[k]);
        }
    }
    #pragma unroll
    for (int k = 0; k < 32; ++k)
        io[(size_t)(row0 + rbase + k) * NC + d] = acc[k];
}

// ---------------------------------------------------------------------------
extern "C" void kernel_launch(void* const* d_in, const int* in_sizes, int n_in,
                              void* d_out, int out_size, void* d_ws, size_t ws_size,
                              hipStream_t stream) {
    const float* xyz   = nullptr;  // 49152
    const float* feats = nullptr;  // 2097152
    const float* W     = nullptr;  // 16384
    for (int k = 0; k < n_in; ++k) {
        if      (in_sizes[k] == NB * 3 * NP)       xyz   = (const float*)d_in[k];
        else if (in_sizes[k] == NB * NP * NC)      feats = (const float*)d_in[k];
        else if (in_sizes[k] == NC * NC)           W     = (const float*)d_in[k];
    }
    float* out = (float*)d_out;

    const size_t need = sizeof(float) * (size_t)(NC * NC);
    if (ws_size >= need) {
        float* Wt = (float*)d_ws;                  // 64 KiB
        knn_pool_kernel<<<NB * NP, NT, 0, stream>>>(xyz, feats, W, Wt, out);
        linear_v3_kernel<<<NB * NP / LROWS, NT, 0, stream>>>(out, Wt);
    } else {
        knn_pool_kernel<<<NB * NP, NT, 0, stream>>>(xyz, feats, W, nullptr, out);
        linear_kernel<<<NB * NP / 64, NT, 0, stream>>>(out, W);
    }
}